// Round 18
// baseline (47.670 us; speedup 1.0000x reference)
//
#include <hip/hip_runtime.h>
#include <hip/hip_bf16.h>

#define B_ 8
#define N_ 16384
#define S_ 1024
#define K_ 32
#define CSTEM 64
#define CPATCH 128
#define INDIM 91
#define LDH 136     // Hs row stride (bf16): 272B -> 2-way (free)

typedef __attribute__((ext_vector_type(8))) short short8v;  // 8 bf16 = 4 VGPRs
typedef __attribute__((ext_vector_type(4))) float f32x4;

static __device__ __forceinline__ unsigned short f2bf(float f) {
  union { float f; unsigned int u; } v; v.f = f;
  return (unsigned short)((v.u + 0x7FFFu + ((v.u >> 16) & 1u)) >> 16);  // RNE
}

static __device__ __forceinline__ short8v cvt8(const float4 a, const float4 b) {
  unsigned short v[8];
  v[0] = f2bf(a.x); v[1] = f2bf(a.y); v[2] = f2bf(a.z); v[3] = f2bf(a.w);
  v[4] = f2bf(b.x); v[5] = f2bf(b.y); v[6] = f2bf(b.z); v[7] = f2bf(b.w);
  return *(const short8v*)v;
}

// PE/rel fragment (verified R8-R17 numerics)
static __device__ __forceinline__ short8v pe_frag(
    float r0, float r1, float r2, int kq)
{
  unsigned short v[8];
  #pragma unroll
  for (int j = 0; j < 8; ++j) {
    const int c = 64 + kq + j;
    float val;
    if (c < 67) {
      val = (c == 64) ? r0 : ((c == 65) ? r1 : r2);
    } else if (c < 91) {
      const int qq = c - 67, d = qq >> 3, rbit = qq & 7, band = rbit & 3;
      const float rel = (d == 0) ? r0 : ((d == 1) ? r1 : r2);
      const float ang = rel * ((float)(1 << band) * 3.14159265358979323846f);
      val = (rbit < 4) ? __sinf(ang) : __cosf(ang);
    } else {
      val = 0.f;
    }
    v[j] = f2bf(val);
  }
  return *(const short8v*)v;
}

// -------- Kernel 0: pack w1/w2 into MFMA B-fragment order (bf16) --------
__global__ __launch_bounds__(256) void pack_weights(
    const float* __restrict__ w1, const float* __restrict__ w2,
    unsigned short* __restrict__ w1p, unsigned short* __restrict__ w2p)
{
  const int id = blockIdx.x * 256 + threadIdx.x;
  if (id < 3 * 8 * 64) {                       // w1: K padded 91->96 (3 ksteps)
    const int l = id & 63, ct = (id >> 6) & 7, ks = id >> 9;
    const int col = 16 * ct + (l & 15);
    const int kb = 32 * ks + (l >> 4) * 8;
    unsigned short v[8];
    #pragma unroll
    for (int j = 0; j < 8; ++j) {
      const int k = kb + j;
      v[j] = (k < INDIM) ? f2bf(w1[k * CPATCH + col]) : (unsigned short)0;
    }
    *(short8v*)&w1p[(size_t)id * 8] = *(const short8v*)v;
  } else if (id < 3 * 8 * 64 + 4 * 8 * 64) {   // w2: 4 ksteps
    const int id2 = id - 3 * 8 * 64;
    const int l = id2 & 63, ct = (id2 >> 6) & 7, ks = id2 >> 9;
    const int col = 16 * ct + (l & 15);
    const int kb = 32 * ks + (l >> 4) * 8;
    unsigned short v[8];
    #pragma unroll
    for (int j = 0; j < 8; ++j) v[j] = f2bf(w2[(kb + j) * CPATCH + col]);
    *(short8v*)&w2p[(size_t)id2 * 8] = *(const short8v*)v;
  }
}

// f32-only test of 4 consecutive points + band mask (verified R17)
#define TEST4FB(V0, V1, V2, MASKVAR, BANDVAR) do {                         \
    MASKVAR = 0u; BANDVAR = 0u;                                            \
    const float X[4] = {(V0).x, (V0).w, (V1).z, (V2).y};                   \
    const float Y[4] = {(V0).y, (V1).x, (V1).w, (V2).z};                   \
    const float Z[4] = {(V0).z, (V1).y, (V2).x, (V2).w};                   \
    _Pragma("unroll")                                                      \
    for (int p = 0; p < 4; ++p) {                                          \
      const float dxf = X[p] - cx, dyf = Y[p] - cy, dzf = Z[p] - cz;       \
      const float d2f = fmaf(dxf, dxf, fmaf(dyf, dyf, dzf * dzf));         \
      if (fabsf(d2f - 0.04f) <= 1e-5f) BANDVAR |= (1u << p);               \
      if (d2f < 0.04f) MASKVAR |= (1u << p);                               \
    }                                                                      \
  } while (0)

// exact f64 fixup for band points (verified expression, decision-identical)
#define FIX4(BANDVAR, MASKVAR, V0, V1, V2) do {                            \
    if (BANDVAR) {                                                         \
      const float X[4] = {(V0).x, (V0).w, (V1).z, (V2).y};                 \
      const float Y[4] = {(V0).y, (V1).x, (V1).w, (V2).z};                 \
      const float Z[4] = {(V0).z, (V1).y, (V2).x, (V2).w};                 \
      _Pragma("unroll")                                                    \
      for (int p = 0; p < 4; ++p) {                                        \
        if ((BANDVAR >> p) & 1u) {                                         \
          const double dx = (double)X[p] - (double)cx;                     \
          const double dy = (double)Y[p] - (double)cy;                     \
          const double dz = (double)Z[p] - (double)cz;                     \
          const bool in64 = (dx * dx + dy * dy + dz * dz) <= (0.2 * 0.2);  \
          MASKVAR = (MASKVAR & ~(1u << p)) | ((unsigned)in64 << p);        \
        }                                                                  \
      }                                                                    \
    }                                                                      \
  } while (0)

#define APPEND4(MASKVAR, POSVAR, I0, V0, V1, V2) do {                      \
    if ((MASKVAR) & 1u) { if ((POSVAR) < K_) { sidx[POSVAR] = (I0) + 0;    \
      sxyz[POSVAR][0] = (V0).x; sxyz[POSVAR][1] = (V0).y;                  \
      sxyz[POSVAR][2] = (V0).z; } ++(POSVAR); }                            \
    if ((MASKVAR) & 2u) { if ((POSVAR) < K_) { sidx[POSVAR] = (I0) + 1;    \
      sxyz[POSVAR][0] = (V0).w; sxyz[POSVAR][1] = (V1).x;                  \
      sxyz[POSVAR][2] = (V1).y; } ++(POSVAR); }                            \
    if ((MASKVAR) & 4u) { if ((POSVAR) < K_) { sidx[POSVAR] = (I0) + 2;    \
      sxyz[POSVAR][0] = (V1).z; sxyz[POSVAR][1] = (V1).w;                  \
      sxyz[POSVAR][2] = (V2).x; } ++(POSVAR); }                            \
    if ((MASKVAR) & 8u) { if ((POSVAR) < K_) { sidx[POSVAR] = (I0) + 3;    \
      sxyz[POSVAR][0] = (V2).y; sxyz[POSVAR][1] = (V2).z;                  \
      sxyz[POSVAR][2] = (V2).w; } ++(POSVAR); }                            \
  } while (0)

#define LDW1(KS, C, T) \
  (*(const short8v*)&w1p[((size_t)((KS) * 8 + 2 * (C) + (T)) * 64 + lane) * 8])
#define LDW2(KS, C, T) \
  (*(const short8v*)&w2p[((size_t)((KS) * 8 + 2 * (C) + (T)) * 64 + lane) * 8])

// -------- Fused, one wave = one query (R17 + entry weight prefetch + prio) -
__global__ __launch_bounds__(64, 4) void fused_wave(
    const float* __restrict__ xyz, const float* __restrict__ pf,
    const float* __restrict__ pc,
    const unsigned short* __restrict__ w1p, const float* __restrict__ b1,
    const unsigned short* __restrict__ w2p, const float* __restrict__ b2,
    float* __restrict__ idx_out, float* __restrict__ out)
{
  const int lane = threadIdx.x;                // 0..63
  const int bs   = blockIdx.x;
  const int b    = bs >> 10;                   // S_ = 1024

  __shared__ int   sidx[K_];
  __shared__ float sxyz[K_][3];
  __shared__ __align__(16) unsigned short Hs[K_][LDH];

  const float* __restrict__ xb  = xyz + (size_t)b * N_ * 3;
  const float* __restrict__ pfb = pf  + (size_t)b * N_ * CSTEM;
  const float cx = pc[bs * 3 + 0];
  const float cy = pc[bs * 3 + 1];
  const float cz = pc[bs * 3 + 2];

  // ---- Entry-issued weight prefetch: latency hides under the ball scan ----
  short8v wA0 = LDW1(0, 0, 0), wA1 = LDW1(0, 0, 1);
  short8v wB0 = LDW1(1, 0, 0), wB1 = LDW1(1, 0, 1);
  short8v wC0 = LDW1(2, 0, 0), wC1 = LDW1(2, 0, 1);
  short8v p0  = LDW2(0, 0, 0), p1  = LDW2(0, 0, 1);

  // ---- Ball scan: 512-pt chunks, prefetched; f32 test + rare f64 fixup ----
  int found = 0;
  {
    const int lo3 = lane * 12;                 // (lane*4)*3 floats
    int base = 0;
    float4 v0 = *(const float4*)&xb[lo3 + 0];
    float4 v1 = *(const float4*)&xb[lo3 + 4];
    float4 v2 = *(const float4*)&xb[lo3 + 8];
    float4 v3 = *(const float4*)&xb[256 * 3 + lo3 + 0];
    float4 v4 = *(const float4*)&xb[256 * 3 + lo3 + 4];
    float4 v5 = *(const float4*)&xb[256 * 3 + lo3 + 8];

    for (;;) {
      const int nb = (base + 512 < N_) ? base + 512 : base;  // clamped prefetch
      const float4 n0 = *(const float4*)&xb[nb * 3 + lo3 + 0];
      const float4 n1 = *(const float4*)&xb[nb * 3 + lo3 + 4];
      const float4 n2 = *(const float4*)&xb[nb * 3 + lo3 + 8];
      const float4 n3 = *(const float4*)&xb[(nb + 256) * 3 + lo3 + 0];
      const float4 n4 = *(const float4*)&xb[(nb + 256) * 3 + lo3 + 4];
      const float4 n5 = *(const float4*)&xb[(nb + 256) * 3 + lo3 + 8];

      unsigned m0, m1, bd0, bd1;
      TEST4FB(v0, v1, v2, m0, bd0);
      TEST4FB(v3, v4, v5, m1, bd1);
      if (__any((int)(bd0 | bd1))) {           // wave-uniform, ~1.5% of iters
        FIX4(bd0, m0, v0, v1, v2);
        FIX4(bd1, m1, v3, v4, v5);
      }

      const int c0 = __popc(m0), c1 = __popc(m1);
      unsigned incl = (unsigned)c0 | ((unsigned)c1 << 16);
      #pragma unroll
      for (int d = 1; d < 64; d <<= 1) {       // packed dual prefix
        const unsigned t = (unsigned)__shfl_up((int)incl, d);
        if (lane >= d) incl += t;
      }
      const unsigned tot = (unsigned)__shfl((int)incl, 63);
      const int t0 = (int)(tot & 0xFFFFu), t1 = (int)(tot >> 16);

      int pos0 = found + (int)(incl & 0xFFFFu) - c0;
      int pos1 = found + t0 + (int)(incl >> 16) - c1;
      const int i0 = base + lane * 4;
      APPEND4(m0, pos0, i0, v0, v1, v2);
      APPEND4(m1, pos1, i0 + 256, v3, v4, v5);

      found += t0 + t1;
      if (found >= K_) break;                  // wave-uniform
      base += 512;
      if (base >= N_) break;
      v0 = n0; v1 = n1; v2 = n2; v3 = n3; v4 = n4; v5 = n5;
    }
  }

  if (lane == 0 && found == 0) {               // none found -> index N-1
    sidx[0] = N_ - 1;
    sxyz[0][0] = xb[(N_ - 1) * 3 + 0];
    sxyz[0][1] = xb[(N_ - 1) * 3 + 1];
    sxyz[0][2] = xb[(N_ - 1) * 3 + 2];
  }
  __threadfence_block();

  // ---- Register-selected padding (no LDS write-back round trip) ----
  const int rfr  = lane & 15;
  const int koff = (lane >> 4) * 8;            // 0,8,16,24

  const int r0 = (rfr < found)      ? sidx[rfr]      : sidx[0];
  const int r1 = (16 + rfr < found) ? sidx[16 + rfr] : sidx[0];

  // issue pf gathers IMMEDIATELY (latency hides under everything below)
  const float4 u00 = *(const float4*)&pfb[(size_t)r0 * CSTEM + koff];
  const float4 u01 = *(const float4*)&pfb[(size_t)r0 * CSTEM + koff + 4];
  const float4 u02 = *(const float4*)&pfb[(size_t)r0 * CSTEM + 32 + koff];
  const float4 u03 = *(const float4*)&pfb[(size_t)r0 * CSTEM + 32 + koff + 4];
  const float4 u10 = *(const float4*)&pfb[(size_t)r1 * CSTEM + koff];
  const float4 u11 = *(const float4*)&pfb[(size_t)r1 * CSTEM + koff + 4];
  const float4 u12 = *(const float4*)&pfb[(size_t)r1 * CSTEM + 32 + koff];
  const float4 u13 = *(const float4*)&pfb[(size_t)r1 * CSTEM + 32 + koff + 4];

  if (lane < K_) {                             // idx output (padded)
    const int vout = (lane < found) ? sidx[lane] : sidx[0];
    idx_out[(size_t)bs * K_ + lane] = (float)vout;
  }

  // padded coords via register selects
  const float sxa = (rfr < found) ? sxyz[rfr][0] : sxyz[0][0];
  const float sya = (rfr < found) ? sxyz[rfr][1] : sxyz[0][1];
  const float sza = (rfr < found) ? sxyz[rfr][2] : sxyz[0][2];
  const float sxb2 = (16 + rfr < found) ? sxyz[16 + rfr][0] : sxyz[0][0];
  const float syb2 = (16 + rfr < found) ? sxyz[16 + rfr][1] : sxyz[0][1];
  const float szb2 = (16 + rfr < found) ? sxyz[16 + rfr][2] : sxyz[0][2];

  const short8v a0k2 = pe_frag(sxa - cx, sya - cy, sza - cz, koff);
  const short8v a1k2 = pe_frag(sxb2 - cx, syb2 - cy, szb2 - cz, koff);
  const short8v a0k0 = cvt8(u00, u01), a0k1 = cvt8(u02, u03);
  const short8v a1k0 = cvt8(u10, u11), a1k1 = cvt8(u12, u13);

  // ---- Layer 1: double-buffered weight sets (entry-prefetched chunk 0) ----
  short8v xA0, xA1, xB0, xB1, xC0, xC1;        // next set

#define L1_CHUNK(C, A0,A1,B0,B1,C0,C1, P0,P1,P2,P3,P4,P5, PREF)            \
  do {                                                                     \
    if (PREF) {                                                            \
      P0 = LDW1(0, (C) + 1, 0); P1 = LDW1(0, (C) + 1, 1);                  \
      P2 = LDW1(1, (C) + 1, 0); P3 = LDW1(1, (C) + 1, 1);                  \
      P4 = LDW1(2, (C) + 1, 0); P5 = LDW1(2, (C) + 1, 1);                  \
    }                                                                      \
    f32x4 acc[2][2] = {};                                                  \
    __builtin_amdgcn_s_setprio(1);                                         \
    acc[0][0] = __builtin_amdgcn_mfma_f32_16x16x32_bf16(a0k0, A0, acc[0][0], 0, 0, 0); \
    acc[0][1] = __builtin_amdgcn_mfma_f32_16x16x32_bf16(a0k0, A1, acc[0][1], 0, 0, 0); \
    acc[1][0] = __builtin_amdgcn_mfma_f32_16x16x32_bf16(a1k0, A0, acc[1][0], 0, 0, 0); \
    acc[1][1] = __builtin_amdgcn_mfma_f32_16x16x32_bf16(a1k0, A1, acc[1][1], 0, 0, 0); \
    acc[0][0] = __builtin_amdgcn_mfma_f32_16x16x32_bf16(a0k1, B0, acc[0][0], 0, 0, 0); \
    acc[0][1] = __builtin_amdgcn_mfma_f32_16x16x32_bf16(a0k1, B1, acc[0][1], 0, 0, 0); \
    acc[1][0] = __builtin_amdgcn_mfma_f32_16x16x32_bf16(a1k1, B0, acc[1][0], 0, 0, 0); \
    acc[1][1] = __builtin_amdgcn_mfma_f32_16x16x32_bf16(a1k1, B1, acc[1][1], 0, 0, 0); \
    acc[0][0] = __builtin_amdgcn_mfma_f32_16x16x32_bf16(a0k2, C0, acc[0][0], 0, 0, 0); \
    acc[0][1] = __builtin_amdgcn_mfma_f32_16x16x32_bf16(a0k2, C1, acc[0][1], 0, 0, 0); \
    acc[1][0] = __builtin_amdgcn_mfma_f32_16x16x32_bf16(a1k2, C0, acc[1][0], 0, 0, 0); \
    acc[1][1] = __builtin_amdgcn_mfma_f32_16x16x32_bf16(a1k2, C1, acc[1][1], 0, 0, 0); \
    __builtin_amdgcn_s_setprio(0);                                         \
    const float bia0 = b1[32 * (C) + rfr];                                 \
    const float bia1 = b1[32 * (C) + 16 + rfr];                            \
    _Pragma("unroll")                                                      \
    for (int rt = 0; rt < 2; ++rt)                                         \
      _Pragma("unroll")                                                    \
      for (int reg = 0; reg < 4; ++reg) {                                  \
        const int row = 16 * rt + (lane >> 4) * 4 + reg;                   \
        Hs[row][32 * (C) + rfr]      = f2bf(fmaxf(acc[rt][0][reg] + bia0, 0.f)); \
        Hs[row][32 * (C) + 16 + rfr] = f2bf(fmaxf(acc[rt][1][reg] + bia1, 0.f)); \
      }                                                                    \
  } while (0)

  L1_CHUNK(0, wA0,wA1,wB0,wB1,wC0,wC1, xA0,xA1,xB0,xB1,xC0,xC1, true);
  L1_CHUNK(1, xA0,xA1,xB0,xB1,xC0,xC1, wA0,wA1,wB0,wB1,wC0,wC1, true);
  L1_CHUNK(2, wA0,wA1,wB0,wB1,wC0,wC1, xA0,xA1,xB0,xB1,xC0,xC1, true);
  L1_CHUNK(3, xA0,xA1,xB0,xB1,xC0,xC1, wA0,wA1,wB0,wB1,wC0,wC1, false);
#undef L1_CHUNK

  // same-wave LDS round-trip: ordered via lgkmcnt, no barrier needed
  short8v hf[8];
  #pragma unroll
  for (int ks = 0; ks < 4; ++ks) {
    hf[ks * 2 + 0] = *(const short8v*)&Hs[rfr][ks * 32 + koff];
    hf[ks * 2 + 1] = *(const short8v*)&Hs[16 + rfr][ks * 32 + koff];
  }

  // ---- Layer 2 + column max: rolling pair-prefetch ((0,0) pre-issued) ----
  short8v q0, q1;

#define L2_STEP(KS, CUR0, CUR1, NXT0, NXT1, NC, NKS, LAST)                 \
  do {                                                                     \
    if (!(LAST)) { NXT0 = LDW2(NKS, NC, 0); NXT1 = LDW2(NKS, NC, 1); }     \
    __builtin_amdgcn_s_setprio(1);                                         \
    acc2[0][0] = __builtin_amdgcn_mfma_f32_16x16x32_bf16(hf[(KS) * 2 + 0], CUR0, acc2[0][0], 0, 0, 0); \
    acc2[0][1] = __builtin_amdgcn_mfma_f32_16x16x32_bf16(hf[(KS) * 2 + 0], CUR1, acc2[0][1], 0, 0, 0); \
    acc2[1][0] = __builtin_amdgcn_mfma_f32_16x16x32_bf16(hf[(KS) * 2 + 1], CUR0, acc2[1][0], 0, 0, 0); \
    acc2[1][1] = __builtin_amdgcn_mfma_f32_16x16x32_bf16(hf[(KS) * 2 + 1], CUR1, acc2[1][1], 0, 0, 0); \
    __builtin_amdgcn_s_setprio(0);                                         \
  } while (0)

  #pragma unroll
  for (int c = 0; c < 4; ++c) {
    f32x4 acc2[2][2] = {};
    L2_STEP(0, p0, p1, q0, q1, c, 1, false);
    L2_STEP(1, q0, q1, p0, p1, c, 2, false);
    L2_STEP(2, p0, p1, q0, q1, c, 3, false);
    L2_STEP(3, q0, q1, p0, p1, c + 1, 0, c == 3);

    float m0 = -3.4e38f, m1 = -3.4e38f;
    #pragma unroll
    for (int rt = 0; rt < 2; ++rt)
      #pragma unroll
      for (int reg = 0; reg < 4; ++reg) {
        m0 = fmaxf(m0, acc2[rt][0][reg]);
        m1 = fmaxf(m1, acc2[rt][1][reg]);
      }
    m0 += b2[32 * c + rfr];
    m1 += b2[32 * c + 16 + rfr];
    m0 = fmaxf(m0, __shfl_xor(m0, 16));
    m0 = fmaxf(m0, __shfl_xor(m0, 32));
    m1 = fmaxf(m1, __shfl_xor(m1, 16));
    m1 = fmaxf(m1, __shfl_xor(m1, 32));
    if (lane < 16) {
      out[(size_t)bs * CPATCH + 32 * c + lane]      = m0;
      out[(size_t)bs * CPATCH + 32 * c + 16 + lane] = m1;
    }
  }
#undef L2_STEP
}

extern "C" void kernel_launch(void* const* d_in, const int* in_sizes, int n_in,
                              void* d_out, int out_size, void* d_ws, size_t ws_size,
                              hipStream_t stream) {
  const float* xyz = (const float*)d_in[0];
  const float* pf  = (const float*)d_in[1];
  const float* pc  = (const float*)d_in[2];
  const float* w1  = (const float*)d_in[3];
  const float* b1  = (const float*)d_in[4];
  const float* w2  = (const float*)d_in[5];
  const float* b2  = (const float*)d_in[6];

  float* out     = (float*)d_out;
  float* idx_out = out + (size_t)B_ * S_ * CPATCH;

  unsigned short* w1p = (unsigned short*)d_ws;          // 96*128 bf16
  unsigned short* w2p = w1p + 96 * 128;                 // 128*128 bf16

  pack_weights<<<14, 256, 0, stream>>>(w1, w2, w1p, w2p);
  fused_wave<<<B_ * S_, 64, 0, stream>>>(xyz, pf, pc, w1p, b1, w2p, b2,
                                         idx_out, out);
}

// Round 19
// 45.194 us; speedup vs baseline: 1.0548x; 1.0548x over previous
//
#include <hip/hip_runtime.h>
#include <hip/hip_bf16.h>

#define B_ 8
#define N_ 16384
#define S_ 1024
#define K_ 32
#define CSTEM 64
#define CPATCH 128
#define INDIM 91
#define LDH 136     // Hs row stride (bf16): 272B -> 2-way (free)

typedef __attribute__((ext_vector_type(8))) short short8v;  // 8 bf16 = 4 VGPRs
typedef __attribute__((ext_vector_type(4))) float f32x4;

static __device__ __forceinline__ unsigned short f2bf(float f) {
  union { float f; unsigned int u; } v; v.f = f;
  return (unsigned short)((v.u + 0x7FFFu + ((v.u >> 16) & 1u)) >> 16);  // RNE
}

static __device__ __forceinline__ short8v cvt8(const float4 a, const float4 b) {
  unsigned short v[8];
  v[0] = f2bf(a.x); v[1] = f2bf(a.y); v[2] = f2bf(a.z); v[3] = f2bf(a.w);
  v[4] = f2bf(b.x); v[5] = f2bf(b.y); v[6] = f2bf(b.z); v[7] = f2bf(b.w);
  return *(const short8v*)v;
}

// PE/rel fragment (verified R8-R18 numerics)
static __device__ __forceinline__ short8v pe_frag(
    float r0, float r1, float r2, int kq)
{
  unsigned short v[8];
  #pragma unroll
  for (int j = 0; j < 8; ++j) {
    const int c = 64 + kq + j;
    float val;
    if (c < 67) {
      val = (c == 64) ? r0 : ((c == 65) ? r1 : r2);
    } else if (c < 91) {
      const int qq = c - 67, d = qq >> 3, rbit = qq & 7, band = rbit & 3;
      const float rel = (d == 0) ? r0 : ((d == 1) ? r1 : r2);
      const float ang = rel * ((float)(1 << band) * 3.14159265358979323846f);
      val = (rbit < 4) ? __sinf(ang) : __cosf(ang);
    } else {
      val = 0.f;
    }
    v[j] = f2bf(val);
  }
  return *(const short8v*)v;
}

// -------- Kernel 0: pack w1/w2 into MFMA B-fragment order (bf16) --------
__global__ __launch_bounds__(256) void pack_weights(
    const float* __restrict__ w1, const float* __restrict__ w2,
    unsigned short* __restrict__ w1p, unsigned short* __restrict__ w2p)
{
  const int id = blockIdx.x * 256 + threadIdx.x;
  if (id < 3 * 8 * 64) {                       // w1: K padded 91->96 (3 ksteps)
    const int l = id & 63, ct = (id >> 6) & 7, ks = id >> 9;
    const int col = 16 * ct + (l & 15);
    const int kb = 32 * ks + (l >> 4) * 8;
    unsigned short v[8];
    #pragma unroll
    for (int j = 0; j < 8; ++j) {
      const int k = kb + j;
      v[j] = (k < INDIM) ? f2bf(w1[k * CPATCH + col]) : (unsigned short)0;
    }
    *(short8v*)&w1p[(size_t)id * 8] = *(const short8v*)v;
  } else if (id < 3 * 8 * 64 + 4 * 8 * 64) {   // w2: 4 ksteps
    const int id2 = id - 3 * 8 * 64;
    const int l = id2 & 63, ct = (id2 >> 6) & 7, ks = id2 >> 9;
    const int col = 16 * ct + (l & 15);
    const int kb = 32 * ks + (l >> 4) * 8;
    unsigned short v[8];
    #pragma unroll
    for (int j = 0; j < 8; ++j) v[j] = f2bf(w2[(kb + j) * CPATCH + col]);
    *(short8v*)&w2p[(size_t)id2 * 8] = *(const short8v*)v;
  }
}

// f32-only test of 4 consecutive points + band mask (verified R17)
#define TEST4FB(V0, V1, V2, MASKVAR, BANDVAR) do {                         \
    MASKVAR = 0u; BANDVAR = 0u;                                            \
    const float X[4] = {(V0).x, (V0).w, (V1).z, (V2).y};                   \
    const float Y[4] = {(V0).y, (V1).x, (V1).w, (V2).z};                   \
    const float Z[4] = {(V0).z, (V1).y, (V2).x, (V2).w};                   \
    _Pragma("unroll")                                                      \
    for (int p = 0; p < 4; ++p) {                                          \
      const float dxf = X[p] - cx, dyf = Y[p] - cy, dzf = Z[p] - cz;       \
      const float d2f = fmaf(dxf, dxf, fmaf(dyf, dyf, dzf * dzf));         \
      if (fabsf(d2f - 0.04f) <= 1e-5f) BANDVAR |= (1u << p);               \
      if (d2f < 0.04f) MASKVAR |= (1u << p);                               \
    }                                                                      \
  } while (0)

// exact f64 fixup for band points (verified expression, decision-identical)
#define FIX4(BANDVAR, MASKVAR, V0, V1, V2) do {                            \
    if (BANDVAR) {                                                         \
      const float X[4] = {(V0).x, (V0).w, (V1).z, (V2).y};                 \
      const float Y[4] = {(V0).y, (V1).x, (V1).w, (V2).z};                 \
      const float Z[4] = {(V0).z, (V1).y, (V2).x, (V2).w};                 \
      _Pragma("unroll")                                                    \
      for (int p = 0; p < 4; ++p) {                                        \
        if ((BANDVAR >> p) & 1u) {                                         \
          const double dx = (double)X[p] - (double)cx;                     \
          const double dy = (double)Y[p] - (double)cy;                     \
          const double dz = (double)Z[p] - (double)cz;                     \
          const bool in64 = (dx * dx + dy * dy + dz * dz) <= (0.2 * 0.2);  \
          MASKVAR = (MASKVAR & ~(1u << p)) | ((unsigned)in64 << p);        \
        }                                                                  \
      }                                                                    \
    }                                                                      \
  } while (0)

#define APPEND4(MASKVAR, POSVAR, I0, V0, V1, V2) do {                      \
    if ((MASKVAR) & 1u) { if ((POSVAR) < K_) { sidx[POSVAR] = (I0) + 0;    \
      sxyz[POSVAR][0] = (V0).x; sxyz[POSVAR][1] = (V0).y;                  \
      sxyz[POSVAR][2] = (V0).z; } ++(POSVAR); }                            \
    if ((MASKVAR) & 2u) { if ((POSVAR) < K_) { sidx[POSVAR] = (I0) + 1;    \
      sxyz[POSVAR][0] = (V0).w; sxyz[POSVAR][1] = (V1).x;                  \
      sxyz[POSVAR][2] = (V1).y; } ++(POSVAR); }                            \
    if ((MASKVAR) & 4u) { if ((POSVAR) < K_) { sidx[POSVAR] = (I0) + 2;    \
      sxyz[POSVAR][0] = (V1).z; sxyz[POSVAR][1] = (V1).w;                  \
      sxyz[POSVAR][2] = (V2).x; } ++(POSVAR); }                            \
    if ((MASKVAR) & 8u) { if ((POSVAR) < K_) { sidx[POSVAR] = (I0) + 3;    \
      sxyz[POSVAR][0] = (V2).y; sxyz[POSVAR][1] = (V2).z;                  \
      sxyz[POSVAR][2] = (V2).w; } ++(POSVAR); }                            \
  } while (0)

#define LDW1(KS, C, T) \
  (*(const short8v*)&w1p[((size_t)((KS) * 8 + 2 * (C) + (T)) * 64 + lane) * 8])
#define LDW2(KS, C, T) \
  (*(const short8v*)&w2p[((size_t)((KS) * 8 + 2 * (C) + (T)) * 64 + lane) * 8])

// -------- Fused, one wave = one query (R17 champion + depth-2 L2 prefetch) -
__global__ __launch_bounds__(64, 4) void fused_wave(
    const float* __restrict__ xyz, const float* __restrict__ pf,
    const float* __restrict__ pc,
    const unsigned short* __restrict__ w1p, const float* __restrict__ b1,
    const unsigned short* __restrict__ w2p, const float* __restrict__ b2,
    float* __restrict__ idx_out, float* __restrict__ out)
{
  const int lane = threadIdx.x;                // 0..63
  const int bs   = blockIdx.x;
  const int b    = bs >> 10;                   // S_ = 1024

  __shared__ int   sidx[K_];
  __shared__ float sxyz[K_][3];
  __shared__ __align__(16) unsigned short Hs[K_][LDH];

  const float* __restrict__ xb  = xyz + (size_t)b * N_ * 3;
  const float* __restrict__ pfb = pf  + (size_t)b * N_ * CSTEM;
  const float cx = pc[bs * 3 + 0];
  const float cy = pc[bs * 3 + 1];
  const float cz = pc[bs * 3 + 2];

  // ---- Ball scan: 512-pt chunks, prefetched; f32 test + rare f64 fixup ----
  int found = 0;
  {
    const int lo3 = lane * 12;                 // (lane*4)*3 floats
    int base = 0;
    float4 v0 = *(const float4*)&xb[lo3 + 0];
    float4 v1 = *(const float4*)&xb[lo3 + 4];
    float4 v2 = *(const float4*)&xb[lo3 + 8];
    float4 v3 = *(const float4*)&xb[256 * 3 + lo3 + 0];
    float4 v4 = *(const float4*)&xb[256 * 3 + lo3 + 4];
    float4 v5 = *(const float4*)&xb[256 * 3 + lo3 + 8];

    for (;;) {
      const int nb = (base + 512 < N_) ? base + 512 : base;  // clamped prefetch
      const float4 n0 = *(const float4*)&xb[nb * 3 + lo3 + 0];
      const float4 n1 = *(const float4*)&xb[nb * 3 + lo3 + 4];
      const float4 n2 = *(const float4*)&xb[nb * 3 + lo3 + 8];
      const float4 n3 = *(const float4*)&xb[(nb + 256) * 3 + lo3 + 0];
      const float4 n4 = *(const float4*)&xb[(nb + 256) * 3 + lo3 + 4];
      const float4 n5 = *(const float4*)&xb[(nb + 256) * 3 + lo3 + 8];

      unsigned m0, m1, bd0, bd1;
      TEST4FB(v0, v1, v2, m0, bd0);
      TEST4FB(v3, v4, v5, m1, bd1);
      if (__any((int)(bd0 | bd1))) {           // wave-uniform, ~1.5% of iters
        FIX4(bd0, m0, v0, v1, v2);
        FIX4(bd1, m1, v3, v4, v5);
      }

      const int c0 = __popc(m0), c1 = __popc(m1);
      unsigned incl = (unsigned)c0 | ((unsigned)c1 << 16);
      #pragma unroll
      for (int d = 1; d < 64; d <<= 1) {       // packed dual prefix
        const unsigned t = (unsigned)__shfl_up((int)incl, d);
        if (lane >= d) incl += t;
      }
      const unsigned tot = (unsigned)__shfl((int)incl, 63);
      const int t0 = (int)(tot & 0xFFFFu), t1 = (int)(tot >> 16);

      int pos0 = found + (int)(incl & 0xFFFFu) - c0;
      int pos1 = found + t0 + (int)(incl >> 16) - c1;
      const int i0 = base + lane * 4;
      APPEND4(m0, pos0, i0, v0, v1, v2);
      APPEND4(m1, pos1, i0 + 256, v3, v4, v5);

      found += t0 + t1;
      if (found >= K_) break;                  // wave-uniform
      base += 512;
      if (base >= N_) break;
      v0 = n0; v1 = n1; v2 = n2; v3 = n3; v4 = n4; v5 = n5;
    }
  }

  if (lane == 0 && found == 0) {               // none found -> index N-1
    sidx[0] = N_ - 1;
    sxyz[0][0] = xb[(N_ - 1) * 3 + 0];
    sxyz[0][1] = xb[(N_ - 1) * 3 + 1];
    sxyz[0][2] = xb[(N_ - 1) * 3 + 2];
  }
  __threadfence_block();

  // ---- Register-selected padding (no LDS write-back round trip) ----
  const int rfr  = lane & 15;
  const int koff = (lane >> 4) * 8;            // 0,8,16,24

  const int r0 = (rfr < found)      ? sidx[rfr]      : sidx[0];
  const int r1 = (16 + rfr < found) ? sidx[16 + rfr] : sidx[0];

  // issue pf gathers IMMEDIATELY (latency hides under everything below)
  const float4 u00 = *(const float4*)&pfb[(size_t)r0 * CSTEM + koff];
  const float4 u01 = *(const float4*)&pfb[(size_t)r0 * CSTEM + koff + 4];
  const float4 u02 = *(const float4*)&pfb[(size_t)r0 * CSTEM + 32 + koff];
  const float4 u03 = *(const float4*)&pfb[(size_t)r0 * CSTEM + 32 + koff + 4];
  const float4 u10 = *(const float4*)&pfb[(size_t)r1 * CSTEM + koff];
  const float4 u11 = *(const float4*)&pfb[(size_t)r1 * CSTEM + koff + 4];
  const float4 u12 = *(const float4*)&pfb[(size_t)r1 * CSTEM + 32 + koff];
  const float4 u13 = *(const float4*)&pfb[(size_t)r1 * CSTEM + 32 + koff + 4];

  if (lane < K_) {                             // idx output (padded)
    const int vout = (lane < found) ? sidx[lane] : sidx[0];
    idx_out[(size_t)bs * K_ + lane] = (float)vout;
  }

  // padded coords via register selects
  const float sxa = (rfr < found) ? sxyz[rfr][0] : sxyz[0][0];
  const float sya = (rfr < found) ? sxyz[rfr][1] : sxyz[0][1];
  const float sza = (rfr < found) ? sxyz[rfr][2] : sxyz[0][2];
  const float sxb2 = (16 + rfr < found) ? sxyz[16 + rfr][0] : sxyz[0][0];
  const float syb2 = (16 + rfr < found) ? sxyz[16 + rfr][1] : sxyz[0][1];
  const float szb2 = (16 + rfr < found) ? sxyz[16 + rfr][2] : sxyz[0][2];

  const short8v a0k2 = pe_frag(sxa - cx, sya - cy, sza - cz, koff);
  const short8v a1k2 = pe_frag(sxb2 - cx, syb2 - cy, szb2 - cz, koff);
  const short8v a0k0 = cvt8(u00, u01), a0k1 = cvt8(u02, u03);
  const short8v a1k0 = cvt8(u10, u11), a1k1 = cvt8(u12, u13);

  // ---- Layer 1: double-buffered weight sets (load c+1 during MFMA c) ----
  short8v wA0, wA1, wB0, wB1, wC0, wC1;        // current set
  short8v xA0, xA1, xB0, xB1, xC0, xC1;        // next set
  wA0 = LDW1(0, 0, 0); wA1 = LDW1(0, 0, 1);
  wB0 = LDW1(1, 0, 0); wB1 = LDW1(1, 0, 1);
  wC0 = LDW1(2, 0, 0); wC1 = LDW1(2, 0, 1);

#define L1_CHUNK(C, A0,A1,B0,B1,C0,C1, P0_,P1_,P2_,P3_,P4_,P5_, PREF)      \
  do {                                                                     \
    if (PREF) {                                                            \
      P0_ = LDW1(0, (C) + 1, 0); P1_ = LDW1(0, (C) + 1, 1);                \
      P2_ = LDW1(1, (C) + 1, 0); P3_ = LDW1(1, (C) + 1, 1);                \
      P4_ = LDW1(2, (C) + 1, 0); P5_ = LDW1(2, (C) + 1, 1);                \
    }                                                                      \
    f32x4 acc[2][2] = {};                                                  \
    acc[0][0] = __builtin_amdgcn_mfma_f32_16x16x32_bf16(a0k0, A0, acc[0][0], 0, 0, 0); \
    acc[0][1] = __builtin_amdgcn_mfma_f32_16x16x32_bf16(a0k0, A1, acc[0][1], 0, 0, 0); \
    acc[1][0] = __builtin_amdgcn_mfma_f32_16x16x32_bf16(a1k0, A0, acc[1][0], 0, 0, 0); \
    acc[1][1] = __builtin_amdgcn_mfma_f32_16x16x32_bf16(a1k0, A1, acc[1][1], 0, 0, 0); \
    acc[0][0] = __builtin_amdgcn_mfma_f32_16x16x32_bf16(a0k1, B0, acc[0][0], 0, 0, 0); \
    acc[0][1] = __builtin_amdgcn_mfma_f32_16x16x32_bf16(a0k1, B1, acc[0][1], 0, 0, 0); \
    acc[1][0] = __builtin_amdgcn_mfma_f32_16x16x32_bf16(a1k1, B0, acc[1][0], 0, 0, 0); \
    acc[1][1] = __builtin_amdgcn_mfma_f32_16x16x32_bf16(a1k1, B1, acc[1][1], 0, 0, 0); \
    acc[0][0] = __builtin_amdgcn_mfma_f32_16x16x32_bf16(a0k2, C0, acc[0][0], 0, 0, 0); \
    acc[0][1] = __builtin_amdgcn_mfma_f32_16x16x32_bf16(a0k2, C1, acc[0][1], 0, 0, 0); \
    acc[1][0] = __builtin_amdgcn_mfma_f32_16x16x32_bf16(a1k2, C0, acc[1][0], 0, 0, 0); \
    acc[1][1] = __builtin_amdgcn_mfma_f32_16x16x32_bf16(a1k2, C1, acc[1][1], 0, 0, 0); \
    const float bia0 = b1[32 * (C) + rfr];                                 \
    const float bia1 = b1[32 * (C) + 16 + rfr];                            \
    _Pragma("unroll")                                                      \
    for (int rt = 0; rt < 2; ++rt)                                         \
      _Pragma("unroll")                                                    \
      for (int reg = 0; reg < 4; ++reg) {                                  \
        const int row = 16 * rt + (lane >> 4) * 4 + reg;                   \
        Hs[row][32 * (C) + rfr]      = f2bf(fmaxf(acc[rt][0][reg] + bia0, 0.f)); \
        Hs[row][32 * (C) + 16 + rfr] = f2bf(fmaxf(acc[rt][1][reg] + bia1, 0.f)); \
      }                                                                    \
  } while (0)

  L1_CHUNK(0, wA0,wA1,wB0,wB1,wC0,wC1, xA0,xA1,xB0,xB1,xC0,xC1, true);
  L1_CHUNK(1, xA0,xA1,xB0,xB1,xC0,xC1, wA0,wA1,wB0,wB1,wC0,wC1, true);
  L1_CHUNK(2, wA0,wA1,wB0,wB1,wC0,wC1, xA0,xA1,xB0,xB1,xC0,xC1, true);
  L1_CHUNK(3, xA0,xA1,xB0,xB1,xC0,xC1, wA0,wA1,wB0,wB1,wC0,wC1, false);
#undef L1_CHUNK

  // ---- L2 steps 0,1 issued BEFORE the Hs read-back (latency overlap) ----
  short8v P0 = LDW2(0, 0, 0), P1 = LDW2(0, 0, 1);   // step 0 (ks0,c0)
  short8v Q0 = LDW2(1, 0, 0), Q1 = LDW2(1, 0, 1);   // step 1 (ks1,c0)
  short8v R0, R1;

  // same-wave LDS round-trip: ordered via lgkmcnt, no barrier needed
  short8v hf[8];
  #pragma unroll
  for (int ks = 0; ks < 4; ++ks) {
    hf[ks * 2 + 0] = *(const short8v*)&Hs[rfr][ks * 32 + koff];
    hf[ks * 2 + 1] = *(const short8v*)&Hs[16 + rfr][ks * 32 + koff];
  }

  // ---- Layer 2 + column max: DEPTH-2 rolling prefetch (3 pair-buffers) ----
  // step s uses buf[s%3]; step s issues the load for step s+2 into buf[(s+2)%3].
#define L2_STEP(KS, CUR0, CUR1, NXT0, NXT1, NKS, NC, PREF)                 \
  do {                                                                     \
    if (PREF) { NXT0 = LDW2(NKS, NC, 0); NXT1 = LDW2(NKS, NC, 1); }        \
    acc2[0][0] = __builtin_amdgcn_mfma_f32_16x16x32_bf16(hf[(KS) * 2 + 0], CUR0, acc2[0][0], 0, 0, 0); \
    acc2[0][1] = __builtin_amdgcn_mfma_f32_16x16x32_bf16(hf[(KS) * 2 + 0], CUR1, acc2[0][1], 0, 0, 0); \
    acc2[1][0] = __builtin_amdgcn_mfma_f32_16x16x32_bf16(hf[(KS) * 2 + 1], CUR0, acc2[1][0], 0, 0, 0); \
    acc2[1][1] = __builtin_amdgcn_mfma_f32_16x16x32_bf16(hf[(KS) * 2 + 1], CUR1, acc2[1][1], 0, 0, 0); \
  } while (0)

#define L2_EPI(C)                                                          \
  do {                                                                     \
    float m0 = -3.4e38f, m1 = -3.4e38f;                                    \
    _Pragma("unroll")                                                      \
    for (int rt = 0; rt < 2; ++rt)                                         \
      _Pragma("unroll")                                                    \
      for (int reg = 0; reg < 4; ++reg) {                                  \
        m0 = fmaxf(m0, acc2[rt][0][reg]);                                  \
        m1 = fmaxf(m1, acc2[rt][1][reg]);                                  \
      }                                                                    \
    m0 += b2[32 * (C) + rfr];                                              \
    m1 += b2[32 * (C) + 16 + rfr];                                         \
    m0 = fmaxf(m0, __shfl_xor(m0, 16));                                    \
    m0 = fmaxf(m0, __shfl_xor(m0, 32));                                    \
    m1 = fmaxf(m1, __shfl_xor(m1, 16));                                    \
    m1 = fmaxf(m1, __shfl_xor(m1, 32));                                    \
    if (lane < 16) {                                                       \
      out[(size_t)bs * CPATCH + 32 * (C) + lane]      = m0;                \
      out[(size_t)bs * CPATCH + 32 * (C) + 16 + lane] = m1;                \
    }                                                                      \
  } while (0)

  {
    f32x4 acc2[2][2];
    // c = 0  (steps 0-3)
    #pragma unroll
    for (int i = 0; i < 2; ++i)
      #pragma unroll
      for (int j = 0; j < 2; ++j) acc2[i][j] = (f32x4){0.f, 0.f, 0.f, 0.f};
    L2_STEP(0, P0, P1, R0, R1, 2, 0, true);    // s0 -> load s2
    L2_STEP(1, Q0, Q1, P0, P1, 3, 0, true);    // s1 -> load s3
    L2_STEP(2, R0, R1, Q0, Q1, 0, 1, true);    // s2 -> load s4
    L2_STEP(3, P0, P1, R0, R1, 1, 1, true);    // s3 -> load s5
    L2_EPI(0);
    // c = 1  (steps 4-7)
    #pragma unroll
    for (int i = 0; i < 2; ++i)
      #pragma unroll
      for (int j = 0; j < 2; ++j) acc2[i][j] = (f32x4){0.f, 0.f, 0.f, 0.f};
    L2_STEP(0, Q0, Q1, P0, P1, 2, 1, true);    // s4 -> load s6
    L2_STEP(1, R0, R1, Q0, Q1, 3, 1, true);    // s5 -> load s7
    L2_STEP(2, P0, P1, R0, R1, 0, 2, true);    // s6 -> load s8
    L2_STEP(3, Q0, Q1, P0, P1, 1, 2, true);    // s7 -> load s9
    L2_EPI(1);
    // c = 2  (steps 8-11)
    #pragma unroll
    for (int i = 0; i < 2; ++i)
      #pragma unroll
      for (int j = 0; j < 2; ++j) acc2[i][j] = (f32x4){0.f, 0.f, 0.f, 0.f};
    L2_STEP(0, R0, R1, Q0, Q1, 2, 2, true);    // s8 -> load s10
    L2_STEP(1, P0, P1, R0, R1, 3, 2, true);    // s9 -> load s11
    L2_STEP(2, Q0, Q1, P0, P1, 0, 3, true);    // s10 -> load s12
    L2_STEP(3, R0, R1, Q0, Q1, 1, 3, true);    // s11 -> load s13
    L2_EPI(2);
    // c = 3  (steps 12-15)
    #pragma unroll
    for (int i = 0; i < 2; ++i)
      #pragma unroll
      for (int j = 0; j < 2; ++j) acc2[i][j] = (f32x4){0.f, 0.f, 0.f, 0.f};
    L2_STEP(0, P0, P1, R0, R1, 2, 3, true);    // s12 -> load s14
    L2_STEP(1, Q0, Q1, P0, P1, 3, 3, true);    // s13 -> load s15
    L2_STEP(2, R0, R1, Q0, Q1, 0, 0, false);   // s14
    L2_STEP(3, P0, P1, R0, R1, 0, 0, false);   // s15
    L2_EPI(3);
  }
#undef L2_STEP
#undef L2_EPI
}

extern "C" void kernel_launch(void* const* d_in, const int* in_sizes, int n_in,
                              void* d_out, int out_size, void* d_ws, size_t ws_size,
                              hipStream_t stream) {
  const float* xyz = (const float*)d_in[0];
  const float* pf  = (const float*)d_in[1];
  const float* pc  = (const float*)d_in[2];
  const float* w1  = (const float*)d_in[3];
  const float* b1  = (const float*)d_in[4];
  const float* w2  = (const float*)d_in[5];
  const float* b2  = (const float*)d_in[6];

  float* out     = (float*)d_out;
  float* idx_out = out + (size_t)B_ * S_ * CPATCH;

  unsigned short* w1p = (unsigned short*)d_ws;          // 96*128 bf16
  unsigned short* w2p = w1p + 96 * 128;                 // 128*128 bf16

  pack_weights<<<14, 256, 0, stream>>>(w1, w2, w1p, w2p);
  fused_wave<<<B_ * S_, 64, 0, stream>>>(xyz, pf, pc, w1p, b1, w2p, b2,
                                         idx_out, out);
}